// Round 3
// baseline (3831.300 us; speedup 1.0000x reference)
//
#include <hip/hip_runtime.h>
#include <math.h>

#define T_ 200

// ---------------- xg GEMM for one C-timestep chunk, one direction, with the
// embedding gather (char_table[ci] * feat_table[fi]) fused into the A-tile load.
// C[rows x 1024] = emb_chunk[rows x 256] @ Wih^T + bias, rows = C*256.
// tiles: 64(M) x 128(N) x 32(K); 256 threads; micro-tile 4x8.
// Chunk local row r holds timestep t = t0 + sgn*r (sgn=+1 fwd, -1 bwd).
__global__ __launch_bounds__(256) void xg_gemm(
    const int* __restrict__ bin, const int* __restrict__ bfe,
    const float* __restrict__ ctab, const float* __restrict__ ftab,
    const float* __restrict__ wih, const float* __restrict__ bias,
    float* __restrict__ xgslot, int t0, int sgn) {
  __shared__ float As[32][68];    // transposed A tile [k][m]
  __shared__ float Bs[32][132];   // transposed B tile [k][n]
  const int tid = threadIdx.x;
  const int m0 = blockIdx.x * 64;
  const int n0 = blockIdx.y * 128;

  const int mm = tid & 15;
  const int nn = tid >> 4;

  float acc[2][4][4];
  #pragma unroll
  for (int q = 0; q < 2; ++q)
    #pragma unroll
    for (int i = 0; i < 4; ++i)
      #pragma unroll
      for (int j2 = 0; j2 < 4; ++j2) acc[q][i][j2] = 0.f;

  const int ra = tid & 63, ka = tid >> 6;    // A stage: row, 8-k group
  const int rb = tid & 127, kb = tid >> 7;   // B stage: row(n), 16-k group

  // fused gather: indices for this thread's A row (fixed across K-loop)
  const int mrow = m0 + ra;
  const int rloc = mrow >> 8;          // local timestep within chunk
  const int bcol = mrow & 255;         // batch index
  const int t = t0 + sgn * rloc;
  const float* cr = ctab + ((size_t)bin[bcol * T_ + t] << 8);
  const float* fr = ftab + ((size_t)bfe[bcol * T_ + t] << 8);

  for (int ks = 0; ks < 256; ks += 32) {
    {
      const float* c0p = cr + ks + ka * 8;
      const float* f0p = fr + ks + ka * 8;
      float4 c0 = *(const float4*)(c0p);
      float4 c1 = *(const float4*)(c0p + 4);
      float4 f0 = *(const float4*)(f0p);
      float4 f1 = *(const float4*)(f0p + 4);
      int kk = ka * 8;
      As[kk + 0][ra] = c0.x * f0.x; As[kk + 1][ra] = c0.y * f0.y;
      As[kk + 2][ra] = c0.z * f0.z; As[kk + 3][ra] = c0.w * f0.w;
      As[kk + 4][ra] = c1.x * f1.x; As[kk + 5][ra] = c1.y * f1.y;
      As[kk + 6][ra] = c1.z * f1.z; As[kk + 7][ra] = c1.w * f1.w;
    }
    {
      const float* src = wih + (size_t)(n0 + rb) * 256 + ks + kb * 16;
      float4 v0 = *(const float4*)(src);
      float4 v1 = *(const float4*)(src + 4);
      float4 v2 = *(const float4*)(src + 8);
      float4 v3 = *(const float4*)(src + 12);
      int kk = kb * 16;
      Bs[kk + 0][rb] = v0.x; Bs[kk + 1][rb] = v0.y; Bs[kk + 2][rb] = v0.z; Bs[kk + 3][rb] = v0.w;
      Bs[kk + 4][rb] = v1.x; Bs[kk + 5][rb] = v1.y; Bs[kk + 6][rb] = v1.z; Bs[kk + 7][rb] = v1.w;
      Bs[kk + 8][rb] = v2.x; Bs[kk + 9][rb] = v2.y; Bs[kk +10][rb] = v2.z; Bs[kk +11][rb] = v2.w;
      Bs[kk +12][rb] = v3.x; Bs[kk +13][rb] = v3.y; Bs[kk +14][rb] = v3.z; Bs[kk +15][rb] = v3.w;
    }
    __syncthreads();
    for (int k = 0; k < 32; ++k) {
      float4 av = *(const float4*)&As[k][mm * 4];
      float4 b0 = *(const float4*)&Bs[k][nn * 4];
      float4 b1 = *(const float4*)&Bs[k][64 + nn * 4];
      float am[4] = {av.x, av.y, av.z, av.w};
      float bv[2][4] = {{b0.x, b0.y, b0.z, b0.w}, {b1.x, b1.y, b1.z, b1.w}};
      #pragma unroll
      for (int i = 0; i < 4; ++i)
        #pragma unroll
        for (int q = 0; q < 2; ++q)
          #pragma unroll
          for (int j2 = 0; j2 < 4; ++j2)
            acc[q][i][j2] += am[i] * bv[q][j2];
    }
    __syncthreads();
  }
  #pragma unroll
  for (int q = 0; q < 2; ++q) {
    int nc = n0 + q * 64 + nn * 4;
    float4 bv = *(const float4*)(bias + nc);
    #pragma unroll
    for (int i = 0; i < 4; ++i) {
      int row = m0 + mm * 4 + i;
      float4 o;
      o.x = acc[q][i][0] + bv.x;
      o.y = acc[q][i][1] + bv.y;
      o.z = acc[q][i][2] + bv.z;
      o.w = acc[q][i][3] + bv.w;
      *(float4*)(xgslot + (size_t)row * 1024 + nc) = o;
    }
  }
}

// ---------------- persistent LSTM chunk: nsteps timesteps in ONE launch.
// grid (16 bc, 8 js, 2 dir) = 256 blocks (all co-resident: 17 KB LDS each).
// Group = (dir,bc): 8 js-blocks sync via device-scope atomic counter per step.
// h-state crosses blocks via agent-scope (sc1) loads/stores -> no L2 flush.
// Whh streamed directly from (hot) L2 each step; c-state in registers.
// Thread tile: 4 gates x 2 j x 4 b, k split 4 ways (ks), in-wave shfl reduce.
__global__ __launch_bounds__(256, 1) void lstm_chunk(
    const float* __restrict__ xgf, const float* __restrict__ xgb,
    const float* __restrict__ whf, const float* __restrict__ whb,
    const int* __restrict__ blen,
    float* __restrict__ hst, float* __restrict__ cst,
    float* __restrict__ hout, unsigned* __restrict__ bar,
    int s0, int nsteps) {
  const int bc = blockIdx.x, js = blockIdx.y, dir = blockIdx.z;
  const int tid = threadIdx.x;
  const int ks = tid & 3;             // k-split lane (bits 0-1 -> shfl_xor 1,2)
  const int bq = (tid >> 2) & 3;      // batch quad
  const int jp = tid >> 4;            // j pair index 0..15
  const int j0 = js * 32 + jp * 2;
  const int grp = dir * 16 + bc;
  const float* wh = dir ? whb : whf;
  const float* xgp = dir ? xgb : xgf;

  __shared__ float h_lds[16 * 260];   // [b][k], row pad 260 (16B-aligned rows)

  // 8 W rows: 4 gates x 2 j (row = g*256 + j), fixed across steps
  const float* wrow[4][2];
  #pragma unroll
  for (int g = 0; g < 4; ++g)
    #pragma unroll
    for (int u = 0; u < 2; ++u)
      wrow[g][u] = wh + ((size_t)(g * 256 + j0 + u)) * 256;

  const int bgbase = bc * 16 + bq * 4;
  int lenr[4];
  #pragma unroll
  for (int b = 0; b < 4; ++b) lenr[b] = blen[bgbase + b];

  float creg[2][4];
  #pragma unroll
  for (int u = 0; u < 2; ++u)
    #pragma unroll
    for (int b = 0; b < 4; ++b)
      creg[u][b] = cst[((size_t)dir * 256 + bgbase + b) * 256 + j0 + u];

  for (int r = 0; r < nsteps; ++r) {
    const int s = s0 + r;
    const int tt = dir ? (199 - s) : s;
    const int rslot = s & 1, wslot = 1 - rslot;

    // ---- stage h (agent-scope loads: producer blocks may be on other XCDs)
    const float* hsrc = hst + (((size_t)(rslot * 2 + dir) * 256) + bc * 16) * 256;
    for (int i = tid; i < 4096; i += 256) {
      int b = i >> 8, col = i & 255;
      h_lds[b * 260 + col] =
          __hip_atomic_load(hsrc + b * 256 + col, __ATOMIC_RELAXED,
                            __HIP_MEMORY_SCOPE_AGENT);
    }
    __syncthreads();

    // ---- xg prefetch (only ks==0 lanes need it)
    float xq[4][2][4];
    if (ks == 0) {
      #pragma unroll
      for (int g = 0; g < 4; ++g)
        #pragma unroll
        for (int u = 0; u < 2; ++u)
          #pragma unroll
          for (int b = 0; b < 4; ++b)
            xq[g][u][b] = xgp[((size_t)r * 256 + bgbase + b) * 1024 +
                              g * 256 + j0 + u];
    }

    // ---- GEMM: acc[g][u][b] = sum_k Whh[g*256+j0+u][k] * h[b][k]
    float acc[4][2][4];
    #pragma unroll
    for (int g = 0; g < 4; ++g)
      #pragma unroll
      for (int u = 0; u < 2; ++u)
        #pragma unroll
        for (int b = 0; b < 4; ++b) acc[g][u][b] = 0.f;

    #pragma unroll 4
    for (int kq = 0; kq < 16; ++kq) {
      const int k = kq * 16 + ks * 4;   // ks-interleaved: full 64B lines per wave
      float4 h4[4];
      #pragma unroll
      for (int b = 0; b < 4; ++b)
        h4[b] = *(const float4*)&h_lds[(bq * 4 + b) * 260 + k];
      #pragma unroll
      for (int g = 0; g < 4; ++g)
        #pragma unroll
        for (int u = 0; u < 2; ++u) {
          float4 w4 = *(const float4*)(wrow[g][u] + k);
          #pragma unroll
          for (int b = 0; b < 4; ++b)
            acc[g][u][b] += w4.x * h4[b].x + w4.y * h4[b].y +
                            w4.z * h4[b].z + w4.w * h4[b].w;
        }
    }

    // ---- reduce over ks (lanes xor 1, 2) — all 4 lanes end identical
    #pragma unroll
    for (int g = 0; g < 4; ++g)
      #pragma unroll
      for (int u = 0; u < 2; ++u)
        #pragma unroll
        for (int b = 0; b < 4; ++b) {
          float v = acc[g][u][b];
          v += __shfl_xor(v, 1);
          v += __shfl_xor(v, 2);
          acc[g][u][b] = v;
        }

    // ---- cell update + stores (ks==0 lanes: 64 threads cover 32 j x 16 b)
    if (ks == 0) {
      #pragma unroll
      for (int u = 0; u < 2; ++u)
        #pragma unroll
        for (int b = 0; b < 4; ++b) {
          float gi = 1.f / (1.f + expf(-(acc[0][u][b] + xq[0][u][b])));
          float gf = 1.f / (1.f + expf(-(acc[1][u][b] + xq[1][u][b])));
          float gg = tanhf(acc[2][u][b] + xq[2][u][b]);
          float go = 1.f / (1.f + expf(-(acc[3][u][b] + xq[3][u][b])));
          float cn = gf * creg[u][b] + gi * gg;
          float hn = go * tanhf(cn);
          const bool mk = tt < lenr[b];
          if (mk) creg[u][b] = cn;
          float hold = h_lds[(bq * 4 + b) * 260 + j0 + u];
          float hsv = mk ? hn : hold;
          const int bg = bgbase + b;
          // next-step h state: agent scope (write-through to coherence point)
          __hip_atomic_store(
              hst + (((size_t)(wslot * 2 + dir) * 256) + bg) * 256 + j0 + u,
              hsv, __ATOMIC_RELAXED, __HIP_MEMORY_SCOPE_AGENT);
          // h_out: consumed only after kernel end -> plain store
          hout[(((size_t)dir * 200 + tt) * 256 + bg) * 256 + j0 + u] =
              mk ? hn : 0.f;
        }
    }

    // ---- group barrier (8 js-blocks of (dir,bc))
    asm volatile("s_waitcnt vmcnt(0)" ::: "memory");  // drain sc1 h stores
    __syncthreads();
    if (tid == 0) {
      __hip_atomic_fetch_add(&bar[grp * 32], 1u, __ATOMIC_RELAXED,
                             __HIP_MEMORY_SCOPE_AGENT);
      const unsigned tgt = 8u * (unsigned)(s + 1);
      while (__hip_atomic_load(&bar[grp * 32], __ATOMIC_RELAXED,
                               __HIP_MEMORY_SCOPE_AGENT) < tgt) {}
    }
    __syncthreads();
  }

  // persist c for next chunk launch (kernel boundary flushes)
  if (ks == 0) {
    #pragma unroll
    for (int u = 0; u < 2; ++u)
      #pragma unroll
      for (int b = 0; b < 4; ++b)
        cst[((size_t)dir * 256 + bgbase + b) * 256 + j0 + u] = creg[u][b];
  }
}

// ---------------- feats[b][t][k] = [hf|hb] . W_tag[k] + b_tag[k]
__global__ __launch_bounds__(256) void feats_kernel(
    const float* __restrict__ h_out, const float* __restrict__ wtag,
    const float* __restrict__ btag, float* __restrict__ feats) {
  __shared__ float hcat[32][512];
  const int t = blockIdx.x, bc = blockIdx.y;
  const int tid = threadIdx.x;
  const float* hf = h_out + (((size_t)0 * 200 + t) * 256 + bc * 32) * 256;
  const float* hb = h_out + (((size_t)1 * 200 + t) * 256 + bc * 32) * 256;
  for (int i = tid; i < 2048; i += 256) {
    int row = i >> 6, c4 = (i & 63) << 2;
    *(float4*)&hcat[row][c4] = *(const float4*)(hf + (size_t)row * 256 + c4);
    *(float4*)&hcat[row][256 + c4] = *(const float4*)(hb + (size_t)row * 256 + c4);
  }
  __syncthreads();
  const int kk = tid & 63;
  const int bg = tid >> 6;
  if (kk < 52) {
    float acc[8];
    #pragma unroll
    for (int i = 0; i < 8; ++i) acc[i] = 0.f;
    const float* wr = wtag + (size_t)kk * 512;
    for (int jq = 0; jq < 128; ++jq) {
      float4 wv = *(const float4*)(wr + jq * 4);
      #pragma unroll
      for (int bi = 0; bi < 8; ++bi) {
        float4 hv = *(const float4*)&hcat[bg * 8 + bi][jq * 4];
        acc[bi] += wv.x * hv.x + wv.y * hv.y + wv.z * hv.z + wv.w * hv.w;
      }
    }
    float bv = btag[kk];
    #pragma unroll
    for (int bi = 0; bi < 8; ++bi)
      feats[(size_t)(bc * 32 + bg * 8 + bi) * 10400 + t * 52 + kk] = acc[bi] + bv;
  }
}

// ---------------- Viterbi: one WG per batch row; bp kept in LDS; np semantics.
__global__ __launch_bounds__(256) void viterbi_kernel(
    const float* __restrict__ feats, const float* __restrict__ trans,
    const int* __restrict__ blen, float* __restrict__ out) {
  const int b = blockIdx.x;
  const int tid = threadIdx.x;
  const int k = tid & 63;
  const int g = tid >> 6;
  __shared__ float trl[52 * 52];
  __shared__ float part[52];
  __shared__ float redv[4][64];
  __shared__ int redi[4][64];
  __shared__ int bp[199][52];
  __shared__ float finals[64];

  for (int i = tid; i < 2704; i += 256) trl[i] = trans[i];
  const float* fb = feats + (size_t)b * 10400;
  const int len = blen[b];
  __syncthreads();
  if (tid < 52) part[tid] = trl[50 * 52 + tid] + fb[tid];   // START row = 50
  __syncthreads();

  for (int t = 1; t < 200; ++t) {
    float mv = -1e30f;
    int mj = 0;
    if (k < 52) {
      const float ftk = fb[t * 52 + k];
      #pragma unroll
      for (int jj = 0; jj < 13; ++jj) {
        const int jdx = g * 13 + jj;
        float cand = (part[jdx] + trl[jdx * 52 + k]) + ftk;  // np eval order
        if (cand > mv) { mv = cand; mj = jdx; }              // first-index ties
      }
    }
    redv[g][k] = mv;
    redi[g][k] = mj;
    __syncthreads();
    if (g == 0 && k < 52) {
      float bv = redv[0][k]; int bj = redi[0][k];
      #pragma unroll
      for (int u = 1; u < 4; ++u)
        if (redv[u][k] > bv) { bv = redv[u][k]; bj = redi[u][k]; }
      bool m = t < len;
      bp[t - 1][k] = m ? bj : k;     // ident when masked
      if (m) part[k] = bv;
    }
    __syncthreads();
  }

  if (g == 0 && k < 52) finals[k] = part[k] + trl[k * 52 + 51];  // STOP col = 51
  __syncthreads();
  if (tid == 0) {
    float bs = finals[0]; int bt = 0;
    for (int kk2 = 1; kk2 < 52; ++kk2)
      if (finals[kk2] > bs) { bs = finals[kk2]; bt = kk2; }
    out[b] = bs;
    int tag = bt;
    float* dec = out + 256 + (size_t)b * 200;
    dec[199] = (199 < len) ? (float)tag : 0.f;
    for (int i = 198; i >= 0; --i) {
      tag = bp[i][tag];
      dec[i] = (i < len) ? (float)tag : 0.f;
    }
  }
}

extern "C" void kernel_launch(void* const* d_in, const int* in_sizes, int n_in,
                              void* d_out, int out_size, void* d_ws, size_t ws_size,
                              hipStream_t stream) {
  const int*   bin  = (const int*)d_in[0];
  const int*   bfe  = (const int*)d_in[1];
  const int*   blen = (const int*)d_in[2];
  // d_in[3] batch_recover: unused. d_in[4] mask: derived from batch_len.
  const float* ctab = (const float*)d_in[5];
  const float* ftab = (const float*)d_in[6];
  const float* wihf = (const float*)d_in[7];
  const float* whhf = (const float*)d_in[8];
  const float* bf   = (const float*)d_in[9];
  const float* wihb = (const float*)d_in[10];
  const float* whhb = (const float*)d_in[11];
  const float* bb   = (const float*)d_in[12];
  const float* wtag = (const float*)d_in[13];
  const float* btag = (const float*)d_in[14];
  const float* trn  = (const float*)d_in[15];

  // ---- workspace layout (floats), sized to fit ws_size ----
  // fixed: hst 262144 + cst 131072 + hout 26214400 + fts 2662400 + bar 1024
  const size_t FIXED_F = 29271040;
  size_t ws_f = ws_size / sizeof(float);
  int C = 1;
  const int cands[8] = {25, 20, 10, 8, 5, 4, 2, 1};
  for (int u = 0; u < 8; ++u) {
    if (FIXED_F + (size_t)2 * cands[u] * 262144 <= ws_f) { C = cands[u]; break; }
  }

  float* ws  = (float*)d_ws;
  float* xgf = ws;                          // C * 262144
  float* xgb = xgf + (size_t)C * 262144;    // C * 262144
  float* hst = xgb + (size_t)C * 262144;    // 262,144 (2 slots x 2 dir x 256 x 256)
  float* cst = hst + 262144;                // 131,072
  float* hout = cst + 131072;               // 26,214,400 (2 dir x 200 x 256 x 256)
  float* fts  = hout + 26214400;            // 2,662,400
  unsigned* bar = (unsigned*)(fts + 2662400); // 1024 u32 (32 groups x 32 stride)
  float* out  = (float*)d_out;

  hipMemsetAsync(hst, 0, (size_t)(262144 + 131072) * sizeof(float), stream);
  hipMemsetAsync(bar, 0, 1024 * sizeof(unsigned), stream);

  const int nchunks = 200 / C;
  for (int c = 0; c < nchunks; ++c) {
    // forward chunk: local row r holds t = c*C + r
    xg_gemm<<<dim3(4 * C, 8), 256, 0, stream>>>(bin, bfe, ctab, ftab, wihf, bf,
                                                xgf, c * C, 1);
    // backward chunk: local row r holds t = (199 - c*C) - r
    xg_gemm<<<dim3(4 * C, 8), 256, 0, stream>>>(bin, bfe, ctab, ftab, wihb, bb,
                                                xgb, 199 - c * C, -1);
    lstm_chunk<<<dim3(16, 8, 2), 256, 0, stream>>>(xgf, xgb, whhf, whhb, blen,
                                                   hst, cst, hout, bar,
                                                   c * C, C);
  }
  feats_kernel<<<dim3(200, 8), 256, 0, stream>>>(hout, wtag, btag, fts);
  viterbi_kernel<<<256, 256, 0, stream>>>(fts, trn, blen, out);
}